// Round 7
// baseline (720.791 us; speedup 1.0000x reference)
//
#include <hip/hip_runtime.h>
#include <math.h>

#define CH 128
#define ETC 3
#define LN_EPS 1e-5f
#define MS (CH * CH)

typedef unsigned short u16;
typedef unsigned int u32;
typedef __attribute__((ext_vector_type(8))) short short8;
typedef __attribute__((ext_vector_type(4))) float f32x4;

__device__ __forceinline__ u16 f2bf(float f) {
    u32 u = __float_as_uint(f);
    u += 0x7FFFu + ((u >> 16) & 1u);
    return (u16)(u >> 16);
}
__device__ __forceinline__ float bflo(u32 u) { return __uint_as_float(u << 16); }
__device__ __forceinline__ float bfhi(u32 u) { return __uint_as_float(u & 0xFFFF0000u); }

__device__ __forceinline__ f32x4 mfma16(short8 a, short8 b, f32x4 c) {
    return __builtin_amdgcn_mfma_f32_16x16x32_bf16(a, b, c, 0, 0, 0);
}
__device__ __forceinline__ short8 ld8(const u16* p) { return *(const short8*)p; }

// ---------------------------------------------------------------------------
// Pack weights: fp32 -> bf16, swizzled to per-lane MFMA B-fragment order.
// Layout: [mat][s(4)][nt(8)][lane(64)][j(8)]   (mat stride = MS u16)
// mats 0-2: Wp_t | 3-8: (Wl0_t, Wr0_t) pairs | 9-11: Wl[0,t]/3 | 12: sum(Wr[0,t])/3
// | 13-15: Wl[1,t]/3 | 16: sum(Wr[1,t])/3.  Also bls[2][128] = sum_t bl[l,t]/3.
// B fragment: lane(q=lane>>4,c=lane&15) holds B[k=s*32+q*8+j][n=nt*16+c]
// ---------------------------------------------------------------------------
__global__ __launch_bounds__(256) void pack_w(
    const float* __restrict__ Wp, const float* __restrict__ Wl0,
    const float* __restrict__ Wr0, const float* __restrict__ Wl,
    const float* __restrict__ Wr, const float* __restrict__ bl,
    u16* __restrict__ Bswz, float* __restrict__ bls)
{
    if (blockIdx.x == 0) {
        int l = threadIdx.x >> 7, i = threadIdx.x & 127;
        bls[threadIdx.x] = (bl[((size_t)l * ETC + 0) * CH + i] +
                            bl[((size_t)l * ETC + 1) * CH + i] +
                            bl[((size_t)l * ETC + 2) * CH + i]) * (1.f / 3.f);
    }
    int grp = blockIdx.x * 256 + threadIdx.x;   // ((mat*4+s)*8+nt)*64 + lane
    if (grp >= 17 * 2048) return;
    int lane = grp & 63;
    int t1 = grp >> 6;
    int nt = t1 & 7, t2 = t1 >> 3;
    int s = t2 & 3, mat = t2 >> 2;
    int q = lane >> 4, c = lane & 15;
    int nn = nt * 16 + c;

    const float* s0;
    const float* s1 = nullptr;
    const float* s2 = nullptr;
    float scale = 1.f;
    if (mat < 3) {
        s0 = Wp + (size_t)mat * MS;
    } else if (mat < 9) {
        int t = (mat - 3) >> 1;
        s0 = ((mat - 3) & 1) ? Wr0 + (size_t)t * MS : Wl0 + (size_t)t * MS;
    } else {
        int l = (mat < 13) ? 0 : 1;
        int mm = mat - (l ? 13 : 9);
        scale = 1.f / 3.f;
        if (mm < 3) s0 = Wl + ((size_t)l * ETC + mm) * MS;
        else {
            s0 = Wr + ((size_t)l * ETC + 0) * MS;
            s1 = s0 + MS;
            s2 = s1 + MS;
        }
    }
    short8 o;
    #pragma unroll
    for (int j = 0; j < 8; ++j) {
        int k = s * 32 + q * 8 + j;
        float v = s0[(size_t)k * CH + nn];
        if (s1) v += s1[(size_t)k * CH + nn] + s2[(size_t)k * CH + nn];
        o[j] = (short)f2bf(v * scale);
    }
    *(short8*)&Bswz[(size_t)grp * 8] = o;
}

// ---------------------------------------------------------------------------
// megaGEMM (A-stationary): block owns 128 rows; A fragments loaded ONCE into
// registers; sweep NC weight chunks (B staged in LDS), write 128 cols each
// into a 512-col row-major bf16 table.
// ---------------------------------------------------------------------------
template<int NC, bool AF32, bool BIASRELU>
__global__ __launch_bounds__(256) void mega_k(
    const void* __restrict__ Ap, const u16* __restrict__ Bs,
    const float* __restrict__ bias, u16* __restrict__ out, int nrows)
{
    __shared__ __align__(16) u16 Bsh[MS];
    const int tid = threadIdx.x;
    const int w = tid >> 6, lane = tid & 63;
    const int q = lane >> 4, cc = lane & 15;
    const int rbase = (blockIdx.x * 4 + w) * 32;

    short8 af[2][4];
    #pragma unroll
    for (int rf = 0; rf < 2; ++rf) {
        int row = rbase + rf * 16 + cc;
        int rcl = min(row, nrows - 1);
        #pragma unroll
        for (int s = 0; s < 4; ++s) {
            if constexpr (AF32) {
                const float* xp = (const float*)Ap + (size_t)rcl * CH + s * 32 + q * 8;
                float4 f0 = *(const float4*)xp;
                float4 f1 = *(const float4*)(xp + 4);
                short8 o;
                o[0] = (short)f2bf(f0.x); o[1] = (short)f2bf(f0.y);
                o[2] = (short)f2bf(f0.z); o[3] = (short)f2bf(f0.w);
                o[4] = (short)f2bf(f1.x); o[5] = (short)f2bf(f1.y);
                o[6] = (short)f2bf(f1.z); o[7] = (short)f2bf(f1.w);
                af[rf][s] = o;
            } else {
                af[rf][s] = ld8((const u16*)Ap + (size_t)rcl * CH + s * 32 + q * 8);
            }
        }
    }

    for (int cb = 0; cb < NC; ++cb) {
        __syncthreads();
        const u16* bsrc = Bs + (size_t)cb * MS;
        #pragma unroll
        for (int i = 0; i < 8; ++i)
            *(short8*)&Bsh[(i * 256 + tid) * 8] = ld8(&bsrc[(i * 256 + tid) * 8]);
        __syncthreads();

        f32x4 acc[2][8] = {};
        #pragma unroll
        for (int s = 0; s < 4; ++s)
            #pragma unroll
            for (int nt = 0; nt < 8; ++nt) {
                short8 bv = *(const short8*)&Bsh[((size_t)(s * 8 + nt) * 64 + lane) * 8];
                acc[0][nt] = mfma16(af[0][s], bv, acc[0][nt]);
                acc[1][nt] = mfma16(af[1][s], bv, acc[1][nt]);
            }

        #pragma unroll
        for (int nt = 0; nt < 8; ++nt) {
            float bb = 0.f;
            if constexpr (BIASRELU) bb = bias[cb * CH + nt * 16 + cc];
            #pragma unroll
            for (int rf = 0; rf < 2; ++rf)
                #pragma unroll
                for (int r = 0; r < 4; ++r) {
                    int row = rbase + rf * 16 + q * 4 + r;
                    float v = acc[rf][nt][r] + bb;
                    if constexpr (BIASRELU) v = fmaxf(v, 0.f);
                    out[(size_t)row * 512 + cb * CH + nt * 16 + cc] = f2bf(v);
                }
        }
    }
}

// ---------------------------------------------------------------------------
// gemm0b: per edge type t (blockIdx.y): C = agg_t @ Wl0_t + x @ Wr0_t + bl0_t,
// row-L2-normalize (incl /3), write normed_t (bf16, npad*128).
// ---------------------------------------------------------------------------
__global__ __launch_bounds__(256) void gemm0b_k(
    const u16* __restrict__ aggm, const float* __restrict__ x,
    const u16* __restrict__ Bswz, const float* __restrict__ bl0,
    u16* __restrict__ normed, int nrows, int npad)
{
    __shared__ __align__(16) u16 Bsh[MS];
    const int t = blockIdx.y;
    const int tid = threadIdx.x;
    const int w = tid >> 6, lane = tid & 63;
    const int q = lane >> 4, cc = lane & 15;
    const int rbase = (blockIdx.x * 4 + w) * 32;
    const u16* A0 = aggm + (size_t)t * npad * CH;

    f32x4 acc[2][8] = {};
    for (int m = 0; m < 2; ++m) {
        __syncthreads();
        const u16* bsrc = Bswz + (size_t)(3 + 2 * t + m) * MS;
        #pragma unroll
        for (int i = 0; i < 8; ++i)
            *(short8*)&Bsh[(i * 256 + tid) * 8] = ld8(&bsrc[(i * 256 + tid) * 8]);
        __syncthreads();

        short8 af[2][4];
        #pragma unroll
        for (int rf = 0; rf < 2; ++rf) {
            int row = rbase + rf * 16 + cc;
            if (m == 0) {
                #pragma unroll
                for (int s = 0; s < 4; ++s)
                    af[rf][s] = ld8(&A0[(size_t)row * CH + s * 32 + q * 8]);
            } else {
                int rcl = min(row, nrows - 1);
                #pragma unroll
                for (int s = 0; s < 4; ++s) {
                    const float* xp = x + (size_t)rcl * CH + s * 32 + q * 8;
                    float4 f0 = *(const float4*)xp;
                    float4 f1 = *(const float4*)(xp + 4);
                    short8 o;
                    o[0] = (short)f2bf(f0.x); o[1] = (short)f2bf(f0.y);
                    o[2] = (short)f2bf(f0.z); o[3] = (short)f2bf(f0.w);
                    o[4] = (short)f2bf(f1.x); o[5] = (short)f2bf(f1.y);
                    o[6] = (short)f2bf(f1.z); o[7] = (short)f2bf(f1.w);
                    af[rf][s] = o;
                }
            }
        }
        #pragma unroll
        for (int s = 0; s < 4; ++s)
            #pragma unroll
            for (int nt = 0; nt < 8; ++nt) {
                short8 bv = *(const short8*)&Bsh[((size_t)(s * 8 + nt) * 64 + lane) * 8];
                acc[0][nt] = mfma16(af[0][s], bv, acc[0][nt]);
                acc[1][nt] = mfma16(af[1][s], bv, acc[1][nt]);
            }
    }

    u16* outp = normed + (size_t)t * npad * CH;
    #pragma unroll
    for (int rf = 0; rf < 2; ++rf) {
        float ss[4] = {0.f, 0.f, 0.f, 0.f};
        #pragma unroll
        for (int nt = 0; nt < 8; ++nt) {
            float bf = bl0[t * CH + nt * 16 + cc];
            #pragma unroll
            for (int r = 0; r < 4; ++r) {
                float v = acc[rf][nt][r] + bf;
                acc[rf][nt][r] = v;
                ss[r] += v * v;
            }
        }
        #pragma unroll
        for (int msk = 1; msk < 16; msk <<= 1)
            #pragma unroll
            for (int r = 0; r < 4; ++r) ss[r] += __shfl_xor(ss[r], msk, 64);
        float sc[4];
        #pragma unroll
        for (int r = 0; r < 4; ++r)
            sc[r] = 1.f / (3.f * fmaxf(sqrtf(ss[r]), 1e-12f));
        #pragma unroll
        for (int nt = 0; nt < 8; ++nt)
            #pragma unroll
            for (int r = 0; r < 4; ++r) {
                int row = rbase + rf * 16 + q * 4 + r;
                outp[(size_t)row * CH + nt * 16 + cc] = f2bf(acc[rf][nt][r] * sc[r]);
            }
    }
}

// ---------------------------------------------------------------------------
// gather3: CSR gather-mean from column-slice t of a 512-col bf16 table into
// a 128-col row-major table. Half-wave (32 lanes) per node, 4-edge unroll.
// ---------------------------------------------------------------------------
__global__ __launch_bounds__(256) void agg3_k(
    const u16* __restrict__ mega, const int* __restrict__ rowptr,
    const int* __restrict__ col, u16* __restrict__ dst, int n,
    int Ecap, unsigned long long dststride)
{
    const int t = blockIdx.y;
    rowptr += (size_t)t * (n + 1);
    col += (size_t)t * Ecap;
    const u16* src = mega + (size_t)t * CH;
    dst += (size_t)t * dststride;

    int gid = blockIdx.x * 256 + threadIdx.x;
    int node = gid >> 5;
    int lane = threadIdx.x & 31;
    if (node >= n) return;
    int s = rowptr[node], e = rowptr[node + 1];
    float a0 = 0.f, a1 = 0.f, a2 = 0.f, a3 = 0.f;
    float b0 = 0.f, b1 = 0.f, b2 = 0.f, b3 = 0.f;
    float c0 = 0.f, c1 = 0.f, c2 = 0.f, c3 = 0.f;
    float d0 = 0.f, d1 = 0.f, d2 = 0.f, d3 = 0.f;
    int j = s;
    const int lo = lane * 4;
    for (; j + 4 <= e; j += 4) {
        int i0 = col[j], i1 = col[j + 1], i2 = col[j + 2], i3 = col[j + 3];
        uint2 v0 = *(const uint2*)&src[(size_t)i0 * 512 + lo];
        uint2 v1 = *(const uint2*)&src[(size_t)i1 * 512 + lo];
        uint2 v2 = *(const uint2*)&src[(size_t)i2 * 512 + lo];
        uint2 v3 = *(const uint2*)&src[(size_t)i3 * 512 + lo];
        a0 += bflo(v0.x); a1 += bfhi(v0.x); a2 += bflo(v0.y); a3 += bfhi(v0.y);
        b0 += bflo(v1.x); b1 += bfhi(v1.x); b2 += bflo(v1.y); b3 += bfhi(v1.y);
        c0 += bflo(v2.x); c1 += bfhi(v2.x); c2 += bflo(v2.y); c3 += bfhi(v2.y);
        d0 += bflo(v3.x); d1 += bfhi(v3.x); d2 += bflo(v3.y); d3 += bfhi(v3.y);
    }
    for (; j < e; ++j) {
        int i0 = col[j];
        uint2 v0 = *(const uint2*)&src[(size_t)i0 * 512 + lo];
        a0 += bflo(v0.x); a1 += bfhi(v0.x); a2 += bflo(v0.y); a3 += bfhi(v0.y);
    }
    a0 += b0 + c0 + d0; a1 += b1 + c1 + d1; a2 += b2 + c2 + d2; a3 += b3 + c3 + d3;
    float inv = 1.f / (float)max(e - s, 1);
    uint2 o;
    o.x = (u32)f2bf(a0 * inv) | ((u32)f2bf(a1 * inv) << 16);
    o.y = (u32)f2bf(a2 * inv) | ((u32)f2bf(a3 * inv) << 16);
    *(uint2*)&dst[(size_t)node * CH + lo] = o;
}

// ---------------------------------------------------------------------------
// merge: sum 3 tables (+ optional z column-slice + bias), relu+LN -> bf16,
// or plain fp32 out. Half-wave per row.
// MODE 0: sum3 -> relu -> LN -> bf16 | 1: +z+bias -> relu -> LN -> bf16
// MODE 2: +z+bias -> fp32
// ---------------------------------------------------------------------------
template<int MODE>
__global__ __launch_bounds__(256) void merge_k(
    const u16* __restrict__ a0, const u16* __restrict__ a1,
    const u16* __restrict__ a2, const u16* __restrict__ zm,
    const float* __restrict__ bias, const float* __restrict__ lg,
    const float* __restrict__ lb, u16* __restrict__ outb,
    float* __restrict__ outf, int n)
{
    int gid = blockIdx.x * 256 + threadIdx.x;
    int node = gid >> 5;
    int lane = threadIdx.x & 31;
    if (node >= n) return;
    const int lo = lane * 4;
    uint2 u0 = *(const uint2*)&a0[(size_t)node * CH + lo];
    uint2 u1 = *(const uint2*)&a1[(size_t)node * CH + lo];
    uint2 u2 = *(const uint2*)&a2[(size_t)node * CH + lo];
    float v0 = bflo(u0.x) + bflo(u1.x) + bflo(u2.x);
    float v1 = bfhi(u0.x) + bfhi(u1.x) + bfhi(u2.x);
    float v2 = bflo(u0.y) + bflo(u1.y) + bflo(u2.y);
    float v3 = bfhi(u0.y) + bfhi(u1.y) + bfhi(u2.y);
    if constexpr (MODE >= 1) {
        uint2 uz = *(const uint2*)&zm[(size_t)node * 512 + 384 + lo];
        float4 bb = *(const float4*)&bias[lo];
        v0 += bflo(uz.x) + bb.x;
        v1 += bfhi(uz.x) + bb.y;
        v2 += bflo(uz.y) + bb.z;
        v3 += bfhi(uz.y) + bb.w;
    }
    if constexpr (MODE == 2) {
        float4 o = make_float4(v0, v1, v2, v3);
        *(float4*)&outf[(size_t)node * CH + lo] = o;
        return;
    }
    v0 = fmaxf(v0, 0.f); v1 = fmaxf(v1, 0.f);
    v2 = fmaxf(v2, 0.f); v3 = fmaxf(v3, 0.f);
    float s1 = v0 + v1 + v2 + v3;
    float s2 = v0 * v0 + v1 * v1 + v2 * v2 + v3 * v3;
    #pragma unroll
    for (int m = 1; m < 32; m <<= 1) {
        s1 += __shfl_xor(s1, m, 64);
        s2 += __shfl_xor(s2, m, 64);
    }
    float mu = s1 * (1.f / 128.f);
    float var = s2 * (1.f / 128.f) - mu * mu;
    float rstd = rsqrtf(var + LN_EPS);
    float4 g = *(const float4*)&lg[lo];
    float4 b = *(const float4*)&lb[lo];
    uint2 o;
    o.x = (u32)f2bf((v0 - mu) * rstd * g.x + b.x) |
          ((u32)f2bf((v1 - mu) * rstd * g.y + b.y) << 16);
    o.y = (u32)f2bf((v2 - mu) * rstd * g.z + b.z) |
          ((u32)f2bf((v3 - mu) * rstd * g.w + b.w) << 16);
    *(uint2*)&outb[(size_t)node * CH + lo] = o;
}

// ---------------------------------------------------------------------------
// CSR construction
// ---------------------------------------------------------------------------
__global__ __launch_bounds__(256) void hist_k(
    const int* __restrict__ edges, int* __restrict__ cnt, int E, int n)
{
    int t = blockIdx.y;
    int e = blockIdx.x * 256 + threadIdx.x;
    if (e >= E) return;
    int dst = edges[(size_t)t * 2 * E + E + e];
    atomicAdd(&cnt[t * n + dst], 1);
}

__global__ __launch_bounds__(256) void scan1_k(
    const int* __restrict__ cnt, int* __restrict__ bsum, int n, int nbs)
{
    int t = blockIdx.y, b = blockIdx.x;
    int i = b * 256 + threadIdx.x;
    int v = (i < n) ? cnt[t * n + i] : 0;
    #pragma unroll
    for (int m = 1; m < 64; m <<= 1) v += __shfl_xor(v, m, 64);
    __shared__ int wsum[4];
    if ((threadIdx.x & 63) == 0) wsum[threadIdx.x >> 6] = v;
    __syncthreads();
    if (threadIdx.x == 0) bsum[t * nbs + b] = wsum[0] + wsum[1] + wsum[2] + wsum[3];
}

__global__ __launch_bounds__(512) void scan2_k(int* __restrict__ bsum, int nbs, int nb)
{
    int t = blockIdx.x;
    int tid = threadIdx.x;
    __shared__ int sh[512];
    int v = (tid < nb) ? bsum[t * nbs + tid] : 0;
    sh[tid] = v;
    __syncthreads();
    for (int off = 1; off < 512; off <<= 1) {
        int x = (tid >= off) ? sh[tid - off] : 0;
        __syncthreads();
        sh[tid] += x;
        __syncthreads();
    }
    if (tid < nb) bsum[t * nbs + tid] = sh[tid] - v;
}

__global__ __launch_bounds__(256) void scan3_k(
    const int* __restrict__ cnt, const int* __restrict__ bsum,
    int* __restrict__ rowptr, int n, int nbs)
{
    int t = blockIdx.y, b = blockIdx.x;
    int tid = threadIdx.x;
    int i = b * 256 + tid;
    __shared__ int sh[256];
    int v = (i < n) ? cnt[t * n + i] : 0;
    sh[tid] = v;
    __syncthreads();
    for (int off = 1; off < 256; off <<= 1) {
        int x = (tid >= off) ? sh[tid - off] : 0;
        __syncthreads();
        sh[tid] += x;
        __syncthreads();
    }
    int excl = sh[tid] - v + bsum[t * nbs + b];
    if (i < n) rowptr[(size_t)t * (n + 1) + i] = excl;
    if (i == n - 1) rowptr[(size_t)t * (n + 1) + n] = excl + v;
}

__global__ __launch_bounds__(256) void fill_k(
    const int* __restrict__ edges, const int* __restrict__ rowptr,
    int* __restrict__ cnt2, int* __restrict__ colbuf, int E, int n)
{
    int t = blockIdx.y;
    int e = blockIdx.x * 256 + threadIdx.x;
    if (e >= E) return;
    int src = edges[(size_t)t * 2 * E + e];
    int dst = edges[(size_t)t * 2 * E + E + e];
    int pos = rowptr[(size_t)t * (n + 1) + dst] + atomicAdd(&cnt2[t * n + dst], 1);
    colbuf[(size_t)t * E + pos] = src;
}

// ---------------------------------------------------------------------------
extern "C" void kernel_launch(void* const* d_in, const int* in_sizes, int n_in,
                              void* d_out, int out_size, void* d_ws, size_t ws_size,
                              hipStream_t stream) {
    const float* x    = (const float*)d_in[0];
    const int*   edges= (const int*)d_in[1];
    const float* Wp   = (const float*)d_in[2];
    const float* bp   = (const float*)d_in[3];
    const float* Wl0  = (const float*)d_in[4];
    const float* bl0  = (const float*)d_in[5];
    const float* Wr0  = (const float*)d_in[6];
    const float* Wl   = (const float*)d_in[7];
    const float* bl   = (const float*)d_in[8];
    const float* Wr   = (const float*)d_in[9];
    const float* ln_g = (const float*)d_in[10];
    const float* ln_b = (const float*)d_in[11];
    float* out = (float*)d_out;

    const int n  = in_sizes[0] / CH;         // 100000
    const int E  = in_sizes[1] / (2 * ETC);  // 500000
    const int npad = ((n + 127) / 128) * 128;
    const int NBS = 512;
    const int nb = (n + 255) / 256;

    // workspace layout (~215 MB)
    char* p = (char*)d_ws;
    u16* hs   = (u16*)p;  p += (size_t)npad * CH * 2;        // 25.6 MB
    u16* mega = (u16*)p;  p += (size_t)npad * 512 * 2;       // 102.5 MB (also normed_t)
    u16* aggm = (u16*)p;  p += (size_t)ETC * npad * CH * 2;  // 76.9 MB
    u16* Bswz = (u16*)p;  p += 17 * (size_t)MS * 2;
    float* bls = (float*)p; p += 256 * 4;
    int* cnt    = (int*)p;  p += (size_t)ETC * n * 4;
    int* rowptr = (int*)p;  p += (size_t)ETC * (n + 1) * 4;
    int* colbuf = (int*)p;  p += (size_t)ETC * E * 4;
    int* bsum   = (int*)p;

    const dim3 b256(256);
    const dim3 ge((E + 255) / 256, ETC);
    const dim3 gs(nb, ETC);
    const int gb = npad / 128;               // 782 GEMM blocks
    const int ga = (n * 32 + 255) / 256;     // 12500 half-wave-per-node blocks
    const unsigned long long astr = (unsigned long long)npad * CH;

    // ---- CSR build ----
    hipMemsetAsync(cnt, 0, (size_t)ETC * n * sizeof(int), stream);
    hist_k<<<ge, b256, 0, stream>>>(edges, cnt, E, n);
    scan1_k<<<gs, b256, 0, stream>>>(cnt, bsum, n, NBS);
    scan2_k<<<ETC, 512, 0, stream>>>(bsum, NBS, nb);
    scan3_k<<<gs, b256, 0, stream>>>(cnt, bsum, rowptr, n, NBS);
    hipMemsetAsync(cnt, 0, (size_t)ETC * n * sizeof(int), stream);
    fill_k<<<ge, b256, 0, stream>>>(edges, rowptr, cnt, colbuf, E, n);

    // ---- pack weights ----
    pack_w<<<136, b256, 0, stream>>>(Wp, Wl0, Wr0, Wl, Wr, bl, Bswz, bls);

    // ---- layer 0 ----
    // proj: mega[:, t*128:...] = relu(x @ Wp_t + bp_t), one A-stationary pass
    mega_k<3, true, true><<<gb, b256, 0, stream>>>(x, Bswz, bp, mega, n);
    // gather per type from proj slices
    agg3_k<<<dim3(ga, ETC), b256, 0, stream>>>(mega, rowptr, colbuf, aggm, n, E, astr);
    // per-type K=256 GEMM + rownorm -> normed_t (aliases mega; proj consumed)
    gemm0b_k<<<dim3(gb, ETC), b256, 0, stream>>>(aggm, x, Bswz, bl0, mega, n, npad);
    merge_k<0><<<ga, b256, 0, stream>>>(mega, mega + astr, mega + 2 * astr,
                                        nullptr, nullptr, ln_g, ln_b, hs, nullptr, n);

    // ---- layer 1 ----
    mega_k<4, false, false><<<gb, b256, 0, stream>>>(hs, Bswz + 9 * (size_t)MS,
                                                     nullptr, mega, n);
    agg3_k<<<dim3(ga, ETC), b256, 0, stream>>>(mega, rowptr, colbuf, aggm, n, E, astr);
    merge_k<1><<<ga, b256, 0, stream>>>(aggm, aggm + astr, aggm + 2 * astr,
                                        mega, bls, ln_g + CH, ln_b + CH, hs, nullptr, n);

    // ---- layer 2 ----
    mega_k<4, false, false><<<gb, b256, 0, stream>>>(hs, Bswz + 13 * (size_t)MS,
                                                     nullptr, mega, n);
    agg3_k<<<dim3(ga, ETC), b256, 0, stream>>>(mega, rowptr, colbuf, aggm, n, E, astr);
    merge_k<2><<<ga, b256, 0, stream>>>(aggm, aggm + astr, aggm + 2 * astr,
                                        mega, bls + CH, nullptr, nullptr, nullptr, out, n);
}